// Round 10
// baseline (74.444 us; speedup 1.0000x reference)
//
#include <hip/hip_runtime.h>
#include <hip/hip_bf16.h>
#include <stdint.h>

#define IN_DIM  1024
#define LOW     128
#define OUT_DIM 1024
#define BATCH   8
#define SEQ     2048

typedef unsigned short u16;
typedef short bf16x8 __attribute__((ext_vector_type(8)));
typedef unsigned short u16x4 __attribute__((ext_vector_type(4)));
typedef float f32x4 __attribute__((ext_vector_type(4)));

__device__ __forceinline__ u16 f2bf(float f) {
    union { float f; uint32_t u; } v;
    v.f = f;
    uint32_t u = v.u;
    return (u16)((u + 0x7fffu + ((u >> 16) & 1u)) >> 16);
}

// s_waitcnt immediates (gfx9/CDNA encoding: vmcnt[3:0],[15:14]; exp[6:4]; lgkm[11:8])
#define WAIT_VM8   0x0F78   // vmcnt <= 8, exp/lgkm unlimited
#define WAIT_VM0   0x0F70   // vmcnt 0
#define WAIT_LGKM0 0xC07F   // lgkmcnt 0, vmcnt unlimited

// ---------------------------------------------------------------------------
// gen_half v9: guaranteed-depth pipeline via global_load_lds into PER-WAVE-
// PRIVATE LDS slots. No barriers in the stream (nothing cross-wave until tb).
//   D: NTOT=128,  MTOT=1024, sh=4   |   U: NTOT=1024, MTOT=128, sh=7
// Block = 256 p-rows (32 m x 8 n), 4 waves; wave owns 4 tiles of 16 rows.
// Per tile: 8 glds (1KB each, linear dest, pre-swizzled source ck^=(row&7))
// -> wait vmcnt<=8 -> 8 ds_read_b128 (swizzled, 2-way=free) -> lgkmcnt(0)
// -> stage tile+2 into freed slot -> f2bf + 4 MFMA (verified R5 math)
// -> tb. Depth 2 * 8KB/wave; 8 waves/CU => 128KB/CU in flight structurally.
// LDS 68KB -> 2 blocks/CU. grid 512 per half.
// ---------------------------------------------------------------------------
__global__ __launch_bounds__(256) void gen_half(const float* __restrict__ src,
                                                const float* __restrict__ kv,
                                                u16* __restrict__ outp,
                                                int NTOT, int MTOT, int sh) {
    __shared__ float sbuf[4 * 2 * 2048];   // 4 waves x 2 slots x 8KB = 64KB
    __shared__ u16 tb[8 * 8 * 32];         // [b][n-local 8][m-local 32], 4KB

    int t = threadIdx.x;
    int rb = blockIdx.x;
    int m0 = (rb >> sh) * 32;
    int n0 = (rb & ((1 << sh) - 1)) * 8;

    int lane = t & 63, w = t >> 6;
    int lr = lane & 15;            // A-row / C-col (batch)
    int hi = lane >> 4;            // k-group / C row-group
    int rsw = lr & 7;              // read-side swizzle == row&7

    // B-fragments: bf16(k[batch=lr][k]), k = ks*32 + hi*8 + j; rows 8..15 = 0
    bf16x8 bfrag[4];
#pragma unroll
    for (int ks = 0; ks < 4; ++ks)
#pragma unroll
        for (int j = 0; j < 8; ++j) {
            float kvf = (lr < 8) ? kv[lr * LOW + ks * 32 + hi * 8 + j] : 0.f;
            bfrag[ks][j] = (short)f2bf(kvf);
        }

    float* wbase = sbuf + w * 2 * 2048;

    // stage tile tau into slot tau&1: glds i covers tile-rows i*2+(lane>>5),
    // 16B-chunk (lane&31); source chunk pre-XOR'd with row&7 (rule #21 pair
    // with the read-side XOR below; LDS dest strictly linear).
#define STAGE(tau) {                                                          \
    float* lb = wbase + ((tau) & 1) * 2048;                                   \
    _Pragma("unroll")                                                         \
    for (int i = 0; i < 8; ++i) {                                             \
        int rt = i * 2 + (lane >> 5);                                         \
        int ck = (lane & 31) ^ (rt & 7);                                      \
        const float* ga = src +                                               \
            ((size_t)(m0 + w * 8 + (tau) * 2 + (rt >> 3)) * NTOT              \
             + n0 + (rt & 7)) * 128 + ck * 4;                                 \
        __builtin_amdgcn_global_load_lds(                                     \
            (const __attribute__((address_space(1))) void*)ga,                \
            (__attribute__((address_space(3))) void*)(lb + i * 256), 16, 0, 0); \
    }                                                                         \
    __builtin_amdgcn_sched_barrier(0);                                        \
}

    STAGE(0)
    STAGE(1)

#pragma unroll
    for (int tau = 0; tau < 4; ++tau) {
        // tile tau resident: all but the most recent 8 glds retired
        if (tau < 3) __builtin_amdgcn_s_waitcnt(WAIT_VM8);
        else         __builtin_amdgcn_s_waitcnt(WAIT_VM0);
        __builtin_amdgcn_sched_barrier(0);

        const float* tp = wbase + (tau & 1) * 2048 + lr * 128;  // row lr
        f32x4 va[4], vb[4];
#pragma unroll
        for (int ks = 0; ks < 4; ++ks) {
            int c0 = ks * 8 + hi * 2;
            va[ks] = *(const f32x4*)(tp + ((c0 ^ rsw) * 4));
            vb[ks] = *(const f32x4*)(tp + (((c0 + 1) ^ rsw) * 4));
        }
        __builtin_amdgcn_sched_barrier(0);
        __builtin_amdgcn_s_waitcnt(WAIT_LGKM0);   // reads done -> slot free
        __builtin_amdgcn_sched_barrier(0);

        if (tau < 2) STAGE(tau + 2)               // overwrite freed slot

        f32x4 acc = (f32x4){0.f, 0.f, 0.f, 0.f};
#pragma unroll
        for (int ks = 0; ks < 4; ++ks) {
            f32x4 v0 = va[ks], v1 = vb[ks];
            bf16x8 afr;
            afr[0] = (short)f2bf(v0.x); afr[1] = (short)f2bf(v0.y);
            afr[2] = (short)f2bf(v0.z); afr[3] = (short)f2bf(v0.w);
            afr[4] = (short)f2bf(v1.x); afr[5] = (short)f2bf(v1.y);
            afr[6] = (short)f2bf(v1.z); afr[7] = (short)f2bf(v1.w);
            acc = __builtin_amdgcn_mfma_f32_16x16x32_bf16(afr, bfrag[ks],
                                                          acc, 0, 0, 0);
        }
        if (lr < 8) {
#pragma unroll
            for (int j = 0; j < 4; ++j) {
                int r = hi * 4 + j;                    // tile row 0..15
                int mm = w * 8 + tau * 2 + (r >> 3);   // block-local m 0..31
                tb[lr * 256 + (r & 7) * 32 + mm] = f2bf(acc[j]);
            }
        }
    }
#undef STAGE

    __syncthreads();   // drains lgkm: tb visible to all waves

    // coalesced flush: 64 chunks (b,n') x 64B (32 m)  [verified R5/R7]
    int c64 = t >> 2, q4 = t & 3;
    int bw = c64 >> 3, np = c64 & 7;
    bf16x8 v = *(const bf16x8*)(tb + bw * 256 + np * 32 + q4 * 8);
    *(bf16x8*)(outp + ((size_t)(bw * NTOT + n0 + np)) * MTOT + m0 + q4 * 8) = v;
}

// ---------------------------------------------------------------------------
// fc1: h[b][s][l] = relu( sum_d x[b][s][d] * D[b][d][l] )  -> bf16
// tile: M=32 (s), N=128 (all l), K-loop 1024 step 64. grid = 8*64 = 512
// ---------------------------------------------------------------------------
__global__ __launch_bounds__(256) void fc1(const float* __restrict__ x,
                                           const u16* __restrict__ DgT,
                                           u16* __restrict__ h) {
    __shared__ u16 As[32][72];
    __shared__ u16 Bs[128][72];
    int t = threadIdx.x;
    int bid = blockIdx.x;
    int b = bid >> 6, st = bid & 63;
    int s0 = st * 32;
    const float* xb = x + ((size_t)b * SEQ + s0) * IN_DIM;
    const u16* Db = DgT + (size_t)b * LOW * IN_DIM;

    int w = t >> 6, lane = t & 63;
    int wm = w >> 1, wn = w & 1;
    int lr = lane & 15, hi = lane >> 4;

    f32x4 acc[4];
#pragma unroll
    for (int nf = 0; nf < 4; ++nf) acc[nf] = (f32x4){0.f, 0.f, 0.f, 0.f};

    int ar = t >> 3, ac = t & 7;
    int brt = t >> 3, bc = t & 7;

    for (int kt = 0; kt < IN_DIM / 64; ++kt) {
        int k0 = kt * 64;
#pragma unroll
        for (int i = 0; i < 2; ++i) {
            float4 v = *(const float4*)(xb + (size_t)ar * IN_DIM + k0 + ac * 4 + i * 32);
            u16x4 o;
            o.x = f2bf(v.x); o.y = f2bf(v.y); o.z = f2bf(v.z); o.w = f2bf(v.w);
            *(u16x4*)(&As[ar][ac * 4 + i * 32]) = o;
        }
#pragma unroll
        for (int i = 0; i < 4; ++i) {
            int row = brt + 32 * i;
            bf16x8 v = *(const bf16x8*)(Db + (size_t)row * IN_DIM + k0 + bc * 8);
            *(bf16x8*)(&Bs[row][bc * 8]) = v;
        }
        __syncthreads();
#pragma unroll
        for (int ks = 0; ks < 2; ++ks) {
            int kk = ks * 32 + hi * 8;
            bf16x8 af = *(const bf16x8*)(&As[wm * 16 + lr][kk]);
#pragma unroll
            for (int nf = 0; nf < 4; ++nf) {
                bf16x8 bf = *(const bf16x8*)(&Bs[wn * 64 + nf * 16 + lr][kk]);
                acc[nf] = __builtin_amdgcn_mfma_f32_16x16x32_bf16(af, bf, acc[nf], 0, 0, 0);
            }
        }
        __syncthreads();
    }
    u16* hb = h + ((size_t)b * SEQ + s0) * LOW;
#pragma unroll
    for (int nf = 0; nf < 4; ++nf) {
        int col = wn * 64 + nf * 16 + lr;
#pragma unroll
        for (int j = 0; j < 4; ++j) {
            int rrow = wm * 16 + hi * 4 + j;
            hb[(size_t)rrow * LOW + col] = f2bf(fmaxf(acc[nf][j], 0.f));
        }
    }
}

// ---------------------------------------------------------------------------
// fc2: out[b][s][o] = sum_l h[b][s][l] * U[b][l][o]   (f32 out)
// tile: 128x128, K=128 staged once. grid = 8*16*8 = 1024
// ---------------------------------------------------------------------------
__global__ __launch_bounds__(256) void fc2(const u16* __restrict__ h,
                                           const u16* __restrict__ UgT,
                                           float* __restrict__ out) {
    __shared__ u16 As[128 * 128];
    __shared__ u16 Bs[128 * 128];
    int t = threadIdx.x;
    int bid = blockIdx.x;
    int b = bid >> 7, st = (bid >> 3) & 15, ot = bid & 7;
    int s0 = st * 128, o0 = ot * 128;
    const u16* hb = h + ((size_t)b * SEQ + s0) * LOW;
    const u16* Ub = UgT + ((size_t)b * OUT_DIM + o0) * LOW;

#pragma unroll
    for (int i = 0; i < 8; ++i) {
        int ch = i * 256 + t;
        int row = ch >> 4, c = ch & 15;
        int swc = c ^ (row & 7);
        *(bf16x8*)(As + row * 128 + swc * 8) = *(const bf16x8*)(hb + (size_t)ch * 8);
        *(bf16x8*)(Bs + row * 128 + swc * 8) = *(const bf16x8*)(Ub + (size_t)ch * 8);
    }
    __syncthreads();

    int w = t >> 6, lane = t & 63;
    int wm = w >> 1, wn = w & 1;
    int lr = lane & 15, lkc = (lane >> 4);

    f32x4 acc[4][4];
#pragma unroll
    for (int mf = 0; mf < 4; ++mf)
#pragma unroll
        for (int nf = 0; nf < 4; ++nf)
            acc[mf][nf] = (f32x4){0.f, 0.f, 0.f, 0.f};

#pragma unroll
    for (int ks = 0; ks < 4; ++ks) {
        bf16x8 af[4], bfr[4];
#pragma unroll
        for (int mf = 0; mf < 4; ++mf) {
            int row = wm * 64 + mf * 16 + lr;
            int swc = (ks * 4 + lkc) ^ (row & 7);
            af[mf] = *(const bf16x8*)(As + row * 128 + swc * 8);
        }
#pragma unroll
        for (int nf = 0; nf < 4; ++nf) {
            int row = wn * 64 + nf * 16 + lr;
            int swc = (ks * 4 + lkc) ^ (row & 7);
            bfr[nf] = *(const bf16x8*)(Bs + row * 128 + swc * 8);
        }
#pragma unroll
        for (int mf = 0; mf < 4; ++mf)
#pragma unroll
            for (int nf = 0; nf < 4; ++nf)
                acc[mf][nf] = __builtin_amdgcn_mfma_f32_16x16x32_bf16(
                    af[mf], bfr[nf], acc[mf][nf], 0, 0, 0);
    }

    float* ob = out + ((size_t)b * SEQ + s0) * OUT_DIM + o0;
#pragma unroll
    for (int mf = 0; mf < 4; ++mf)
#pragma unroll
        for (int nf = 0; nf < 4; ++nf) {
            int col = wn * 64 + nf * 16 + lr;
#pragma unroll
            for (int j = 0; j < 4; ++j) {
                int rrow = wm * 64 + mf * 16 + (lane >> 4) * 4 + j;
                ob[(size_t)rrow * OUT_DIM + col] = acc[mf][nf][j];
            }
        }
}

extern "C" void kernel_launch(void* const* d_in, const int* in_sizes, int n_in,
                              void* d_out, int out_size, void* d_ws, size_t ws_size,
                              hipStream_t stream) {
    const float* x  = (const float*)d_in[0];
    const float* kv = (const float*)d_in[1];
    const float* Dm = (const float*)d_in[2];
    const float* Um = (const float*)d_in[3];
    float* out = (float*)d_out;

    u16* DgT  = (u16*)d_ws;                                   // 2 MB
    u16* UgT  = DgT + (size_t)BATCH * LOW * IN_DIM;           // 2 MB
    u16* hbuf = UgT + (size_t)BATCH * OUT_DIM * LOW;          // 4 MB

    gen_half<<<dim3(512), dim3(256), 0, stream>>>(Dm, kv, DgT, 128, 1024, 4);
    gen_half<<<dim3(512), dim3(256), 0, stream>>>(Um, kv, UgT, 1024, 128, 7);
    fc1<<<dim3(512), dim3(256), 0, stream>>>(x, DgT, hbuf);
    fc2<<<dim3(1024), dim3(256), 0, stream>>>(hbuf, UgT, out);
}